// Round 3
// baseline (554.254 us; speedup 1.0000x reference)
//
#include <hip/hip_runtime.h>

#define TB 128  // 2 waves: wave0 = forward chain, wave1 = backward chain

__device__ __forceinline__ float fast_sigmoid(float x) {
  float e = __expf(-x);
  return __builtin_amdgcn_rcpf(1.f + e);
}
__device__ __forceinline__ float fast_tanh(float x) {
  float e = __expf(-2.f * x);
  return fmaf(2.f, __builtin_amdgcn_rcpf(1.f + e), -1.f);
}

// Gate layout: lane l in [0,4H): type = l/H (0:i, 1:f, 2:g, 3:o), cell j = l%H.
// Exchanges: x1 = shfl_xor(a, 2H) pairs i<->g, f<->o. i-lane computes p = i*g.
// x2 = shfl_xor(p, H) delivers p to the f-lane, which owns c_j/h_j state.
// One LDS round-trip per step: f-lanes write h, all lanes read h[0..H-1].
template<int D, int H, int T, int INS, int OUTS, bool POOL, bool TOUT>
__device__ __forceinline__ void scan_core(const float* wr /*[D]*/,
                                          const float* hr /*[H]*/,
                                          float bb,
                                          const float* in_buf,  // [T][INS]
                                          float* out_buf,
                                          int wave, int lane,
                                          float* h_lds) {
  const bool isCell = (lane >= H) && (lane < 2 * H);   // f-lanes hold c,h
  const bool isG = (lane >= 2 * H) && (lane < 3 * H);  // g-gate -> tanh
  if (lane < H) h_lds[lane] = 0.f;
  __builtin_amdgcn_wave_barrier();

  const int dt = wave ? -1 : 1;
  int t = wave ? (T - 1) : 0;

  float curA[D], curB[D];
  auto ldin = [&](float* dst, int tt) {
    if (tt < 0) tt = 0;
    if (tt > T - 1) tt = T - 1;
    const float* p = in_buf + tt * INS;
#pragma unroll
    for (int i = 0; i < D; i += 4) *(float4*)(dst + i) = *(const float4*)(p + i);
  };
  auto xwdot = [&](const float* c) {
    float a0 = bb, a1 = 0.f, a2 = 0.f, a3 = 0.f;
#pragma unroll
    for (int i = 0; i < D; i += 4) {
      a0 = fmaf(wr[i + 0], c[i + 0], a0);
      a1 = fmaf(wr[i + 1], c[i + 1], a1);
      a2 = fmaf(wr[i + 2], c[i + 2], a2);
      a3 = fmaf(wr[i + 3], c[i + 3], a3);
    }
    return (a0 + a1) + (a2 + a3);
  };

  ldin(curA, t);
  ldin(curB, t + dt);
  float xw = xwdot(curA);
  float cs = 0.f, pm = 0.f;

  auto body = [&](int s, float* curNext, float* curLoad) {
    // recurrent dot (4 independent partials), h broadcast from LDS
    float r0 = xw, r1 = 0.f, r2 = 0.f, r3 = 0.f;
#pragma unroll
    for (int i = 0; i < H; i += 4) {
      float4 h4 = *(const float4*)(h_lds + i);
      r0 = fmaf(hr[i + 0], h4.x, r0);
      r1 = fmaf(hr[i + 1], h4.y, r1);
      r2 = fmaf(hr[i + 2], h4.z, r2);
      r3 = fmaf(hr[i + 3], h4.w, r3);
    }
    float acc = (r0 + r1) + (r2 + r3);
    // i,f,o -> sigmoid; g -> tanh = 2*sigmoid(2x)-1
    float u = isG ? 2.f * acc : acc;
    float sg = fast_sigmoid(u);
    float a = isG ? fmaf(2.f, sg, -1.f) : sg;
    // register exchanges replace the gate LDS round-trip
    float x1 = __shfl_xor(a, 2 * H);
    float p = a * x1;
    float x2 = __shfl_xor(p, H);
    // pipeline: next step's input dot + depth-2 prefetch fill the stall window
    xw = xwdot(curNext);
    ldin(curLoad, t + 2 * dt);
    if (isCell) {
      cs = fmaf(a, cs, x2);             // c = f*c + i*g
      float hv = x1 * fast_tanh(cs);    // h = o * tanh(c)
      h_lds[lane - H] = hv;
      int j = lane - H;
      if (TOUT) {
        out_buf[(wave * H + j) * T + t] = hv;
      } else if (POOL) {
        if (s & 1) out_buf[(t >> 1) * OUTS + wave * H + j] = fmaxf(pm, hv);
        else pm = hv;
      } else {
        out_buf[t * OUTS + wave * H + j] = hv;
      }
    }
    __builtin_amdgcn_wave_barrier();
    t += dt;
  };

  for (int s = 0; s < T; s += 2) {  // T always even: ping-pong without copies
    body(s, curB, curA);
    body(s + 1, curA, curB);
  }
}

template<int D, int H>
__device__ __forceinline__ void load_wb(const float* __restrict__ wih,
                                        const float* __restrict__ whh,
                                        const float* __restrict__ bias,
                                        int lane, float* wr, float* hr, float& bb) {
  constexpr int G = 4 * H;
#pragma unroll
  for (int i = 0; i < D; ++i) wr[i] = 0.f;
#pragma unroll
  for (int i = 0; i < H; ++i) hr[i] = 0.f;
  bb = 0.f;
  if (lane < G) {
    const float* p = wih + lane * D;
#pragma unroll
    for (int i = 0; i < D; i += 4) {
      float4 v = *(const float4*)(p + i);
      wr[i] = v.x; wr[i + 1] = v.y; wr[i + 2] = v.z; wr[i + 3] = v.w;
    }
    const float* q = whh + lane * H;
#pragma unroll
    for (int i = 0; i < H; ++i) hr[i] = q[i];
    bb = bias[lane];
  }
}

__global__ __launch_bounds__(TB) void lstm_all(
    const float* __restrict__ x,
    const float* __restrict__ conv_w, const float* __restrict__ conv_b,
    const float* __restrict__ bn_g, const float* __restrict__ bn_b,
    const float* __restrict__ bn_m, const float* __restrict__ bn_v,
    const float* __restrict__ w1a_ih, const float* __restrict__ w1a_hh, const float* __restrict__ b1a,
    const float* __restrict__ w1b_ih, const float* __restrict__ w1b_hh, const float* __restrict__ b1b,
    const float* __restrict__ w2a_ih, const float* __restrict__ w2a_hh, const float* __restrict__ b2a,
    const float* __restrict__ w2b_ih, const float* __restrict__ w2b_hh, const float* __restrict__ b2b,
    const float* __restrict__ w3_ih, const float* __restrict__ w3_hh, const float* __restrict__ b3,
    float* __restrict__ out, float* __restrict__ ws, int row0) {
  const int row = row0 + blockIdx.x;
  const int tid = threadIdx.x;
  const int wave = tid >> 6;
  const int lane = tid & 63;

  // L reused: phase1 xs[512][12] (24KB), phase2 [256][32] (32KB), phase3 [128][16]
  __shared__ __align__(16) float L[8192];
  __shared__ __align__(16) float w2c[64][11];  // conv_w * inv (BN folded)
  __shared__ float b2c[64];
  __shared__ __align__(16) float h_lds[2][16];

  float* A = ws + (size_t)blockIdx.x * 16384;  // 64 KiB per row

  // stage x[row] (11x512) transposed into LDS; zero the pad column
  float (*xs)[12] = (float(*)[12])L;
  const float* xrow = x + (size_t)row * 5632;
  for (int i = tid; i < 5632; i += TB) {
    int c = i >> 9;
    int t = i & 511;
    xs[t][c] = xrow[i];
  }
  for (int i = tid; i < 512; i += TB) xs[i][11] = 0.f;
  // fold BN into conv
  if (tid < 64) {
    float inv = bn_g[tid] * rsqrtf(bn_v[tid] + 1e-5f);
    for (int c = 0; c < 11; ++c) w2c[tid][c] = conv_w[tid * 11 + c] * inv;
    b2c[tid] = fmaf(conv_b[tid] - bn_m[tid], inv, bn_b[tid]);
  }
  __syncthreads();

  // fold conv+BN into L1a input weights: Weff[g][c] = sum_d wih[g][d]*w2c[d][c]
  float weff[12];
  float beff;
  {
#pragma unroll
    for (int c = 0; c < 12; ++c) weff[c] = 0.f;
    const float* wih = w1a_ih + wave * 4096 + lane * 64;
    beff = b1a[wave * 64 + lane];
    for (int d = 0; d < 64; ++d) {
      float wd = wih[d];
      beff = fmaf(wd, b2c[d], beff);
#pragma unroll
      for (int c = 0; c < 11; ++c) weff[c] = fmaf(wd, w2c[d][c], weff[c]);
    }
  }
  float hrw[16];
  {
    const float* q = w1a_hh + wave * 1024 + lane * 16;
#pragma unroll
    for (int i = 0; i < 16; ++i) hrw[i] = q[i];
  }
  // L1a: xs (LDS, padded D=12) -> A [512][32]
  scan_core<12, 16, 512, 12, 32, false, false>(weff, hrw, beff, &xs[0][0], A,
                                               wave, lane, h_lds[wave]);
  __syncthreads();

  {
    float wr[32], hr[16], bb;
    load_wb<32, 16>(w1b_ih + wave * 2048, w1b_hh + wave * 1024, b1b + wave * 64,
                    lane, wr, hr, bb);
    // L1b + pool: A [512][32] -> L [256][32]
    scan_core<32, 16, 512, 32, 32, true, false>(wr, hr, bb, A, L, wave, lane, h_lds[wave]);
  }
  __syncthreads();

  {
    float wr[32], hr[8], bb;
    load_wb<32, 8>(w2a_ih + wave * 1024, w2a_hh + wave * 256, b2a + wave * 32,
                   lane, wr, hr, bb);
    // L2a: L [256][32] -> A [256][16]
    scan_core<32, 8, 256, 32, 16, false, false>(wr, hr, bb, L, A, wave, lane, h_lds[wave]);
  }
  __syncthreads();

  {
    float wr[16], hr[8], bb;
    load_wb<16, 8>(w2b_ih + wave * 512, w2b_hh + wave * 256, b2b + wave * 32,
                   lane, wr, hr, bb);
    // L2b + pool: A [256][16] -> L [128][16]
    scan_core<16, 8, 256, 16, 16, true, false>(wr, hr, bb, A, L, wave, lane, h_lds[wave]);
  }
  __syncthreads();

  {
    float wr[16], hr[4], bb;
    load_wb<16, 4>(w3_ih + wave * 256, w3_hh + wave * 64, b3 + wave * 16,
                   lane, wr, hr, bb);
    // L3: L [128][16] -> out[row][ch][t] directly (transposed store)
    scan_core<16, 4, 128, 16, 8, false, true>(wr, hr, bb, L, out + (size_t)row * 1024,
                                              wave, lane, h_lds[wave]);
  }
}

extern "C" void kernel_launch(void* const* d_in, const int* in_sizes, int n_in,
                              void* d_out, int out_size, void* d_ws, size_t ws_size,
                              hipStream_t stream) {
  const float* x      = (const float*)d_in[0];
  const float* conv_w = (const float*)d_in[1];
  const float* conv_b = (const float*)d_in[2];
  const float* bn_g   = (const float*)d_in[3];
  const float* bn_b   = (const float*)d_in[4];
  const float* bn_m   = (const float*)d_in[5];
  const float* bn_v   = (const float*)d_in[6];
  const float* w1a_ih = (const float*)d_in[7];
  const float* w1a_hh = (const float*)d_in[8];
  const float* b1a    = (const float*)d_in[9];
  const float* w1b_ih = (const float*)d_in[10];
  const float* w1b_hh = (const float*)d_in[11];
  const float* b1b    = (const float*)d_in[12];
  const float* w2a_ih = (const float*)d_in[13];
  const float* w2a_hh = (const float*)d_in[14];
  const float* b2a    = (const float*)d_in[15];
  const float* w2b_ih = (const float*)d_in[16];
  const float* w2b_hh = (const float*)d_in[17];
  const float* b2b    = (const float*)d_in[18];
  const float* w3_ih  = (const float*)d_in[19];
  const float* w3_hh  = (const float*)d_in[20];
  const float* b3     = (const float*)d_in[21];

  const size_t per_row_bytes = 16384 * sizeof(float);  // 64 KiB
  int rows_per = (int)(ws_size / per_row_bytes);
  if (rows_per < 1) rows_per = 1;
  if (rows_per > 1024) rows_per = 1024;

  for (int r0 = 0; r0 < 1024; r0 += rows_per) {
    int n = 1024 - r0;
    if (n > rows_per) n = rows_per;
    lstm_all<<<n, TB, 0, stream>>>(x, conv_w, conv_b, bn_g, bn_b, bn_m, bn_v,
                                   w1a_ih, w1a_hh, b1a, w1b_ih, w1b_hh, b1b,
                                   w2a_ih, w2a_hh, b2a, w2b_ih, w2b_hh, b2b,
                                   w3_ih, w3_hh, b3,
                                   (float*)d_out, (float*)d_ws, r0);
  }
}

// Round 5
// 517.500 us; speedup vs baseline: 1.0710x; 1.0710x over previous
//
#include <hip/hip_runtime.h>

#define TB 128  // 2 waves; L1: wave0=fwd, wave1=bwd. L2/L3: wave0 carries both dirs.

typedef float v2f __attribute__((ext_vector_type(2)));

__device__ __forceinline__ float exp2_fast(float x) {
  return __builtin_amdgcn_exp2f(x);
}

// Gate layout within a direction's lane group: tau = wl/H (0:i 1:f 2:g 3:o), cell j = wl%H.
// Per step: one transposed-gate LDS round trip + one h LDS round trip.
// All lanes compute c/h for cell j = wl%H redundantly (masked lanes issue anyway).
template<int D, int H, int T, int INS, int OUTS, bool POOL, bool TOUT>
__device__ __forceinline__ void scan_core(const float* wr, const float* hr,
                                          float bb, float am, float ab,
                                          const float* in_buf, float* out_buf,
                                          int dir, int wl,
                                          float* h_base, float* gT) {
  constexpr int SH = (H == 16) ? 4 : (H == 8) ? 3 : 2;
  const int j = wl & (H - 1);
  const int tau = wl >> SH;
  const bool act = (wl < 4 * H);
  if (wl < H) h_base[wl] = 0.f;
  __builtin_amdgcn_wave_barrier();

  int t = dir ? (T - 1) : 0;
  const int dt = dir ? -1 : 1;

  float curA[D], curB[D];
  auto ldin = [&](float* dst, int tt) {
    tt = tt < 0 ? 0 : (tt > T - 1 ? T - 1 : tt);
    const float* p = in_buf + tt * INS;
#pragma unroll
    for (int i = 0; i < D; i += 4) *(float4*)(dst + i) = *(const float4*)(p + i);
  };
  auto xwdot = [&](const float* c) -> float {
    v2f q0 = {bb, 0.f}, q1 = {0.f, 0.f};
#pragma unroll
    for (int i = 0; i < D; i += 4) {
      q0 = __builtin_elementwise_fma(*(const v2f*)(wr + i), *(const v2f*)(c + i), q0);
      q1 = __builtin_elementwise_fma(*(const v2f*)(wr + i + 2), *(const v2f*)(c + i + 2), q1);
    }
    v2f qs = q0 + q1;
    return qs.x + qs.y;
  };

  ldin(curA, t);
  ldin(curB, t + dt);
  float xw = xwdot(curA);
  float cs = 0.f, pm = 0.f;
  float* gTj = gT + 4 * j;

  auto body = [&](int s, float* curNext, float* curLoad) {
    // recurrent dot: h broadcast from LDS, packed FMA
    v2f r0 = {xw, 0.f}, r1 = {0.f, 0.f};
#pragma unroll
    for (int i = 0; i < H; i += 4) {
      float4 h4 = *(const float4*)(h_base + i);
      r0 = __builtin_elementwise_fma(*(const v2f*)(hr + i), (v2f){h4.x, h4.y}, r0);
      r1 = __builtin_elementwise_fma(*(const v2f*)(hr + i + 2), (v2f){h4.z, h4.w}, r1);
    }
    v2f rs = r0 + r1;
    float acc = rs.x + rs.y;
    // weights pre-scaled by log2e (2*log2e for g): sg = sigma(x) (or sigma(2x))
    float e2 = exp2_fast(-acc);
    float sg = __builtin_amdgcn_rcpf(1.f + e2);
    float a = fmaf(am, sg, ab);  // i,f,o: a=sg ; g: a=2sg-1=tanh
    if (act) gT[4 * j + tau] = a;  // transposed gate write (1 ds_write_b32)
    __builtin_amdgcn_wave_barrier();
    float4 g4 = *(const float4*)gTj;  // all 4 gates of cell j (1 ds_read_b128)
    // fill the DS-latency window with next step's input dot + prefetch
    xw = xwdot(curNext);
    ldin(curLoad, t + 2 * dt);
    cs = fmaf(g4.y, cs, g4.x * g4.z);                 // c = f*c + i*g
    float ec = exp2_fast(-2.885390082f * cs);         // exp2(-2c*log2e)
    float sc = __builtin_amdgcn_rcpf(1.f + ec);
    float th = fmaf(2.f, sc, -1.f);                   // tanh(c)
    float hv = g4.w * th;                             // h = o * tanh(c)
    if (wl < H) {
      h_base[wl] = hv;
      if (TOUT) {
        out_buf[(dir * H + wl) * T + t] = hv;
      } else if (POOL) {
        if (s & 1) out_buf[(t >> 1) * OUTS + dir * H + wl] = fmaxf(pm, hv);
        else pm = hv;
      } else {
        out_buf[t * OUTS + dir * H + wl] = hv;
      }
    }
    __builtin_amdgcn_wave_barrier();
    t += dt;
  };

  for (int s = 0; s < T; s += 2) {  // T even: register ping-pong
    body(s, curB, curA);
    body(s + 1, curA, curB);
  }
}

// Load + pre-scale weights: rows are [2][4H][.] ; k = log2e (2*log2e for g-gate).
template<int D, int H>
__device__ __forceinline__ void load_wb(const float* __restrict__ wih,
                                        const float* __restrict__ whh,
                                        const float* __restrict__ bias,
                                        int dir, int wl,
                                        float* wr, float* hr, float& bb,
                                        float& am, float& ab) {
  constexpr int G = 4 * H;
  constexpr int SH = (H == 16) ? 4 : (H == 8) ? 3 : 2;
  constexpr float L2E = 1.4426950408889634f;
#pragma unroll
  for (int i = 0; i < D; ++i) wr[i] = 0.f;
#pragma unroll
  for (int i = 0; i < H; ++i) hr[i] = 0.f;
  bb = 0.f;
  const bool isg = ((wl >> SH) == 2) && (wl < G);
  const float k = isg ? 2.f * L2E : L2E;
  am = isg ? 2.f : 1.f;
  ab = isg ? -1.f : 0.f;
  if (wl < G) {
    const int row = dir * G + wl;
    const float* p = wih + row * D;
#pragma unroll
    for (int i = 0; i < D; i += 4) {
      float4 v = *(const float4*)(p + i);
      wr[i] = v.x * k; wr[i + 1] = v.y * k; wr[i + 2] = v.z * k; wr[i + 3] = v.w * k;
    }
    const float* q = whh + row * H;
#pragma unroll
    for (int i = 0; i < H; ++i) hr[i] = q[i] * k;
    bb = bias[row] * k;
  }
}

__global__ __launch_bounds__(TB) void lstm_all(
    const float* __restrict__ x,
    const float* __restrict__ conv_w, const float* __restrict__ conv_b,
    const float* __restrict__ bn_g, const float* __restrict__ bn_b,
    const float* __restrict__ bn_m, const float* __restrict__ bn_v,
    const float* __restrict__ w1a_ih, const float* __restrict__ w1a_hh, const float* __restrict__ b1a,
    const float* __restrict__ w1b_ih, const float* __restrict__ w1b_hh, const float* __restrict__ b1b,
    const float* __restrict__ w2a_ih, const float* __restrict__ w2a_hh, const float* __restrict__ b2a,
    const float* __restrict__ w2b_ih, const float* __restrict__ w2b_hh, const float* __restrict__ b2b,
    const float* __restrict__ w3_ih, const float* __restrict__ w3_hh, const float* __restrict__ b3,
    float* __restrict__ out, float* __restrict__ ws, int row0) {
  const int row = row0 + blockIdx.x;
  const int tid = threadIdx.x;
  const int wave = tid >> 6;
  const int lane = tid & 63;

  // LB overlays: phase1 xs[512][12] (6144f), then L1b out [256][32] (8192f),
  // then L2b out [128][16] (2048f).
  __shared__ __align__(16) float LB[8192];
  __shared__ __align__(16) float w2c[64][11];
  __shared__ float b2c[64];
  __shared__ __align__(16) float hb[32];    // h state, stride 16 per dir
  __shared__ __align__(16) float gT[128];   // transposed gates, 64 per dir

  float* A = ws + (size_t)blockIdx.x * 16384;  // 64 KiB per row

  // stage x[row] (11x512) transposed into LDS; zero pad col
  float (*xs)[12] = (float(*)[12])LB;
  const float* xrow = x + (size_t)row * 5632;
  for (int i = tid; i < 5632; i += TB) {
    int c = i >> 9, t = i & 511;
    xs[t][c] = xrow[i];
  }
  for (int i = tid; i < 512; i += TB) xs[i][11] = 0.f;
  if (tid < 64) {
    float inv = bn_g[tid] * rsqrtf(bn_v[tid] + 1e-5f);
    for (int c = 0; c < 11; ++c) w2c[tid][c] = conv_w[tid * 11 + c] * inv;
    b2c[tid] = fmaf(conv_b[tid] - bn_m[tid], inv, bn_b[tid]);
  }
  __syncthreads();

  // ---- L1a: conv+BN folded into 12-wide effective weights; both waves (dir=wave)
  {
    constexpr float L2E = 1.4426950408889634f;
    float weff[12], beff;
#pragma unroll
    for (int c = 0; c < 12; ++c) weff[c] = 0.f;
    const float* wih = w1a_ih + wave * 4096 + lane * 64;
    beff = b1a[wave * 64 + lane];
    for (int d = 0; d < 64; ++d) {
      float wd = wih[d];
      beff = fmaf(wd, b2c[d], beff);
#pragma unroll
      for (int c = 0; c < 11; ++c) weff[c] = fmaf(wd, w2c[d][c], weff[c]);
    }
    const bool isg = (lane >= 32) && (lane < 48);
    const float k = isg ? 2.f * L2E : L2E;
#pragma unroll
    for (int c = 0; c < 12; ++c) weff[c] *= k;
    beff *= k;
    float am = isg ? 2.f : 1.f, ab = isg ? -1.f : 0.f;
    float hrw[16];
    const float* q = w1a_hh + wave * 1024 + lane * 16;
#pragma unroll
    for (int i = 0; i < 16; ++i) hrw[i] = q[i] * k;
    scan_core<12, 16, 512, 12, 32, false, false>(weff, hrw, beff, am, ab,
        &xs[0][0], A, wave, lane, hb + wave * 16, gT + wave * 64);
  }
  __syncthreads();

  // ---- L1b + pool: A [512][32] -> LB [256][32]; both waves
  {
    float wr[32], hr[16], bb, am, ab;
    load_wb<32, 16>(w1b_ih, w1b_hh, b1b, wave, lane, wr, hr, bb, am, ab);
    scan_core<32, 16, 512, 32, 32, true, false>(wr, hr, bb, am, ab,
        A, LB, wave, lane, hb + wave * 16, gT + wave * 64);
  }
  __syncthreads();

  // ---- L2a: LB [256][32] -> A [256][16]; merged single wave (dir = lane>>5)
  if (wave == 0) {
    const int dir = lane >> 5, wl = lane & 31;
    float wr[32], hr[8], bb, am, ab;
    load_wb<32, 8>(w2a_ih, w2a_hh, b2a, dir, wl, wr, hr, bb, am, ab);
    scan_core<32, 8, 256, 32, 16, false, false>(wr, hr, bb, am, ab,
        LB, A, dir, wl, hb + dir * 16, gT + dir * 64);
  }
  __syncthreads();

  // ---- L2b + pool: A [256][16] -> LB [128][16]; merged
  if (wave == 0) {
    const int dir = lane >> 5, wl = lane & 31;
    float wr[16], hr[8], bb, am, ab;
    load_wb<16, 8>(w2b_ih, w2b_hh, b2b, dir, wl, wr, hr, bb, am, ab);
    scan_core<16, 8, 256, 16, 16, true, false>(wr, hr, bb, am, ab,
        A, LB, dir, wl, hb + dir * 16, gT + dir * 64);
  }
  __syncthreads();

  // ---- L3: LB [128][16] -> out[row][ch][t]; merged
  if (wave == 0) {
    const int dir = lane >> 5, wl = lane & 31;
    float wr[16], hr[4], bb, am, ab;
    load_wb<16, 4>(w3_ih, w3_hh, b3, dir, wl, wr, hr, bb, am, ab);
    scan_core<16, 4, 128, 16, 8, false, true>(wr, hr, bb, am, ab,
        LB, out + (size_t)row * 1024, dir, wl, hb + dir * 16, gT + dir * 64);
  }
}

extern "C" void kernel_launch(void* const* d_in, const int* in_sizes, int n_in,
                              void* d_out, int out_size, void* d_ws, size_t ws_size,
                              hipStream_t stream) {
  const float* x      = (const float*)d_in[0];
  const float* conv_w = (const float*)d_in[1];
  const float* conv_b = (const float*)d_in[2];
  const float* bn_g   = (const float*)d_in[3];
  const float* bn_b   = (const float*)d_in[4];
  const float* bn_m   = (const float*)d_in[5];
  const float* bn_v   = (const float*)d_in[6];
  const float* w1a_ih = (const float*)d_in[7];
  const float* w1a_hh = (const float*)d_in[8];
  const float* b1a    = (const float*)d_in[9];
  const float* w1b_ih = (const float*)d_in[10];
  const float* w1b_hh = (const float*)d_in[11];
  const float* b1b    = (const float*)d_in[12];
  const float* w2a_ih = (const float*)d_in[13];
  const float* w2a_hh = (const float*)d_in[14];
  const float* b2a    = (const float*)d_in[15];
  const float* w2b_ih = (const float*)d_in[16];
  const float* w2b_hh = (const float*)d_in[17];
  const float* b2b    = (const float*)d_in[18];
  const float* w3_ih  = (const float*)d_in[19];
  const float* w3_hh  = (const float*)d_in[20];
  const float* b3     = (const float*)d_in[21];

  const size_t per_row_bytes = 16384 * sizeof(float);
  int rows_per = (int)(ws_size / per_row_bytes);
  if (rows_per < 1) rows_per = 1;
  if (rows_per > 1024) rows_per = 1024;

  for (int r0 = 0; r0 < 1024; r0 += rows_per) {
    int n = 1024 - r0;
    if (n > rows_per) n = rows_per;
    lstm_all<<<n, TB, 0, stream>>>(x, conv_w, conv_b, bn_g, bn_b, bn_m, bn_v,
                                   w1a_ih, w1a_hh, b1a, w1b_ih, w1b_hh, b1b,
                                   w2a_ih, w2a_hh, b2a, w2b_ih, w2b_hh, b2b,
                                   w3_ih, w3_hh, b3,
                                   (float*)d_out, (float*)d_ws, r0);
  }
}